// Round 18
// baseline (219.285 us; speedup 1.0000x reference)
//
#include <hip/hip_runtime.h>
#include <hip/hip_bf16.h>

#define NB 4
#define NC 512
#define NS 4096
#define NH 8
#define HD 64
#define NG 32
#define CPG 16
#define QKC 1024   // Q+K channels in qk buffer
#define CQF 0.18033688f  // 0.125 * log2(e), folded into Q weights

typedef __attribute__((ext_vector_type(8))) short bf16x8;
typedef __attribute__((ext_vector_type(4))) float f32x4;
typedef __attribute__((ext_vector_type(16))) float f32x16;

__device__ __forceinline__ unsigned short f2bf(float f) {
  union { float f; unsigned int u; } v; v.f = f;
  unsigned int r = v.u + 0x7FFFu + ((v.u >> 16) & 1u);
  return (unsigned short)(r >> 16);
}

__device__ __forceinline__ unsigned short f2bf_rn(float f) {
  union { __hip_bfloat16 h; unsigned short u; } cv;
  cv.h = __float2bfloat16(f);
  return cv.u;
}

// async global->LDS, 16B per lane. LDS base must be wave-uniform; source is per-lane.
__device__ __forceinline__ void gload16(const unsigned short* g, unsigned short* s) {
  __builtin_amdgcn_global_load_lds(
      (const __attribute__((address_space(1))) unsigned int*)g,
      (__attribute__((address_space(3))) unsigned int*)s, 16, 0, 0);
}

// ---------------- K1: fused prep: gn partial stats (blocks 0..511) + weight cvt (blocks 512..1023) ----------------
__global__ __launch_bounds__(256) void prep_k(const float* __restrict__ x,
                                              float* __restrict__ pstats,
                                              const float* __restrict__ wq,
                                              const float* __restrict__ wp,
                                              unsigned short* __restrict__ wqb,
                                              unsigned short* __restrict__ wpb) {
  int bid = blockIdx.x;
  if (bid < NB * NG * 4) {
    int bgq = bid;
    const float4* xp = (const float4*)(x + (size_t)bgq * (CPG * NS / 4));
    float s = 0.f, s2 = 0.f;
    #pragma unroll 4
    for (int i = threadIdx.x; i < CPG * NS / 16; i += 256) {
      float4 v = xp[i];
      s  += v.x + v.y + v.z + v.w;
      s2 += v.x * v.x + v.y * v.y + v.z * v.z + v.w * v.w;
    }
    #pragma unroll
    for (int off = 32; off > 0; off >>= 1) {
      s  += __shfl_down(s, off);
      s2 += __shfl_down(s2, off);
    }
    __shared__ float rs[4], rs2[4];
    int wid = threadIdx.x >> 6;
    if ((threadIdx.x & 63) == 0) { rs[wid] = s; rs2[wid] = s2; }
    __syncthreads();
    if (threadIdx.x == 0) {
      pstats[bgq * 2]     = rs[0] + rs[1] + rs[2] + rs[3];
      pstats[bgq * 2 + 1] = rs2[0] + rs2[1] + rs2[2] + rs2[3];
    }
  } else {
    const int nq8 = 3 * NC * NC / 8, np8 = NC * NC / 8, se8 = NC * NC / 8;
    int i = (bid - NB * NG * 4) * 256 + threadIdx.x;
    if (i >= nq8 + np8) return;
    const float* src;
    unsigned short* dst;
    float sc;
    int j;
    if (i < nq8) { src = wq; dst = wqb; j = i; sc = (i < se8) ? CQF : 1.0f; }
    else         { src = wp; dst = wpb; j = i - nq8; sc = 1.0f; }
    const float4* s = (const float4*)src + (size_t)j * 2;
    float4 a = s[0], b = s[1];
    ushort4 u0 = make_ushort4(f2bf_rn(a.x * sc), f2bf_rn(a.y * sc),
                              f2bf_rn(a.z * sc), f2bf_rn(a.w * sc));
    ushort4 u1 = make_ushort4(f2bf_rn(b.x * sc), f2bf_rn(b.y * sc),
                              f2bf_rn(b.z * sc), f2bf_rn(b.w * sc));
    uint4 o;
    o.x = (unsigned)u0.x | ((unsigned)u0.y << 16);
    o.y = (unsigned)u0.z | ((unsigned)u0.w << 16);
    o.z = (unsigned)u1.x | ((unsigned)u1.y << 16);
    o.w = (unsigned)u1.z | ((unsigned)u1.w << 16);
    *((uint4*)dst + j) = o;
  }
}

// ---------------- K2: normalize + transpose -> ht[b][s][c] (bf16); combines partial stats ----------------
__global__ __launch_bounds__(256) void gn_apply_k(const float* __restrict__ x,
                                                  const float* __restrict__ pstats,
                                                  const float* __restrict__ nw,
                                                  const float* __restrict__ nb,
                                                  unsigned short* __restrict__ ht) {
  int st = blockIdx.x, ct = blockIdx.y, b = blockIdx.z;
  int c0 = ct * 64, s0 = st * 64;
  __shared__ unsigned short lds[64][72];
  for (int idx = threadIdx.x; idx < 1024; idx += 256) {
    int row = idx >> 4, c4 = idx & 15;
    int c = c0 + row;
    int gi = (b * NG + (c >> 4)) * 4;
    const float4* pq = (const float4*)(pstats + gi * 2);
    float4 p01 = pq[0], p23 = pq[1];
    float sum = p01.x + p01.z + p23.x + p23.z;
    float ssq = p01.y + p01.w + p23.y + p23.w;
    float inv_n = 1.0f / (CPG * NS);
    float mu = sum * inv_n;
    float var = ssq * inv_n - mu * mu;
    float rstd = rsqrtf(var + 1e-5f);
    float sw = nw[c] * rstd;
    float sb = nb[c] - mu * sw;
    float4 v = *(const float4*)(x + ((size_t)b * NC + c) * NS + s0 + c4 * 4);
    ushort4 u = make_ushort4(f2bf(v.x * sw + sb), f2bf(v.y * sw + sb),
                             f2bf(v.z * sw + sb), f2bf(v.w * sw + sb));
    *(ushort4*)&lds[row][c4 * 4] = u;
  }
  __syncthreads();
  for (int idx = threadIdx.x; idx < 1024; idx += 256) {
    int i = idx >> 4, ch = idx & 15;
    ushort4 u = make_ushort4(lds[ch * 4 + 0][i], lds[ch * 4 + 1][i],
                             lds[ch * 4 + 2][i], lds[ch * 4 + 3][i]);
    *(ushort4*)(ht + ((size_t)b * NS + s0 + i) * NC + c0 + ch * 4) = u;
  }
}

// ---------------- K3: QKV GEMM, global_load_lds staging (BK=64, XOR-swizzled LDS) ----------------
__global__ __launch_bounds__(256) void qkv_gemm_k(const unsigned short* __restrict__ ht,
                                                  const unsigned short* __restrict__ wqb,
                                                  const float* __restrict__ bq,
                                                  unsigned short* __restrict__ qk,
                                                  unsigned short* __restrict__ vt) {
  int b = blockIdx.z;
  int m0 = blockIdx.x * 128, n0 = blockIdx.y * 128;  // m = s, n = o
  __shared__ unsigned short alds[128 * 64];
  __shared__ unsigned short blds[128 * 64];
  const unsigned short* A = ht + (size_t)b * NS * NC;
  int tid = threadIdx.x;
  int l = tid & 63, w = tid >> 6;
  int wr = w >> 1, wc = w & 1;
  int lm = l & 15, lg = l >> 4;
  int lrow = l >> 3, lcb = l & 7;
  f32x4 acc[4][4];
  #pragma unroll
  for (int mi = 0; mi < 4; mi++)
    #pragma unroll
    for (int ni = 0; ni < 4; ni++) acc[mi][ni] = (f32x4){0.f, 0.f, 0.f, 0.f};

  for (int k0 = 0; k0 < NC; k0 += 64) {
    #pragma unroll
    for (int j = 0; j < 4; j++) {
      int row = w * 32 + j * 8 + lrow;
      int scb = lcb ^ (row & 7);
      gload16(A   + (size_t)(m0 + row) * NC + k0 + scb * 8, &alds[(w * 4 + j) * 512]);
      gload16(wqb + (size_t)(n0 + row) * NC + k0 + scb * 8, &blds[(w * 4 + j) * 512]);
    }
    __syncthreads();
    #pragma unroll
    for (int ks = 0; ks < 2; ks++) {
      bf16x8 af[4], bfr[4];
      #pragma unroll
      for (int mi = 0; mi < 4; mi++) {
        int row = wr * 64 + mi * 16 + lm;
        af[mi] = *(const bf16x8*)&alds[((row << 6) + (ks << 5) + (lg << 3)) ^ ((row & 7) << 3)];
      }
      #pragma unroll
      for (int ni = 0; ni < 4; ni++) {
        int row = wc * 64 + ni * 16 + lm;
        bfr[ni] = *(const bf16x8*)&blds[((row << 6) + (ks << 5) + (lg << 3)) ^ ((row & 7) << 3)];
      }
      #pragma unroll
      for (int mi = 0; mi < 4; mi++)
        #pragma unroll
        for (int ni = 0; ni < 4; ni++)
          acc[mi][ni] = __builtin_amdgcn_mfma_f32_16x16x32_bf16(af[mi], bfr[ni], acc[mi][ni], 0, 0, 0);
    }
    __syncthreads();
  }
  if (n0 < QKC) {
    #pragma unroll
    for (int mi = 0; mi < 4; mi++) {
      #pragma unroll
      for (int ni = 0; ni < 4; ni++) {
        int o = n0 + wc * 64 + ni * 16 + lm;
        float bias = bq[o];
        if (o < NC) bias *= CQF;  // Q rows: weight pre-scaled, bias scaled to match
        #pragma unroll
        for (int q = 0; q < 4; q++) {
          int s = m0 + wr * 64 + mi * 16 + lg * 4 + q;
          qk[((size_t)b * NS + s) * QKC + o] = f2bf(acc[mi][ni][q] + bias);
        }
      }
    }
  } else {
    #pragma unroll
    for (int mi = 0; mi < 4; mi++) {
      int s0 = m0 + wr * 64 + mi * 16 + lg * 4;
      #pragma unroll
      for (int ni = 0; ni < 4; ni++) {
        int o = n0 + wc * 64 + ni * 16 + lm;
        float bias = bq[o];
        int dg = o - QKC;  // 0..511 == h*64+d
        ushort4 u = make_ushort4(f2bf(acc[mi][ni][0] + bias), f2bf(acc[mi][ni][1] + bias),
                                 f2bf(acc[mi][ni][2] + bias), f2bf(acc[mi][ni][3] + bias));
        *(ushort4*)(vt + ((size_t)b * NC + dg) * NS + s0) = u;
      }
    }
  }
}

// ---------------- K4: flash attention ----------------
// 8 waves / 256 Q-rows; gload_lds staging; XCD-pinned; KVBLK=128/round.
// l via lane-local VALU sum (swapped layout: each lane's exp values all belong to
// query i=l31) -> kills acc_l (16 regs) + ones (4 regs) -> ~112 unified regs/wave
// -> 4 waves/SIMD -> two 8-wave blocks co-resident per CU.
__global__ __launch_bounds__(512) void attn_k(const unsigned short* __restrict__ qk,
                                              const unsigned short* __restrict__ vt,
                                              unsigned short* __restrict__ ob) {
  int bid = blockIdx.x;
  int xcd = bid & 7, g = bid >> 3;
  int pair = xcd * 4 + (g >> 4);   // bijective: 32 (b,h) pairs, 4 per XCD
  int qt = g & 15;
  int h = pair & 7, b = pair >> 3;
  int tid = threadIdx.x;
  int l = tid & 63, w = tid >> 6;  // w in 0..7
  int l31 = l & 31, hi = l >> 5;
  // [buf:2][K0:4096|V0:4096|K1:4096|V1:4096] shorts = 64 KB
  __shared__ unsigned short slds[32768];
  const unsigned short* qkb = qk + (size_t)b * NS * QKC;
  const unsigned short* vtb = vt + ((size_t)b * NC + h * HD) * NS;
  int iw = qt * 256 + w * 32;

  bf16x8 fq[4];
  #pragma unroll
  for (int kk = 0; kk < 4; kk++)
    fq[kk] = *(const bf16x8*)(qkb + (size_t)(iw + l31) * QKC + h * HD + kk * 16 + hi * 8);

  int rb = (((l31 << 6) + (hi << 3)) ^ ((l31 & 7) << 3));
  int rbk[4] = { rb, rb ^ 16, rb ^ 32, rb ^ 48 };

  // gload staging: wave w covers rows w*8..w*8+8 of each 64-row subtile
  int kr = w * 8 + (l >> 3);
  int scb = (l & 7) ^ (l >> 3);    // (l&7) ^ (kr&7); +64-row offsets preserve kr&7
  const unsigned short* kgp = qkb + NC + h * HD + (size_t)kr * QKC + scb * 8;
  const unsigned short* vgp = vtb + (size_t)kr * NS + scb * 8;
  unsigned short* kd = &slds[w * 512];          // K0 dest (buf0)
  unsigned short* vd = &slds[4096 + w * 512];   // V0 dest

  f32x16 acc_o0 = {}, acc_o1 = {};
  float l_run = 0.f;

  // prologue: round-0 tile (128 j) -> buf0
  gload16(kgp, kd);
  gload16(kgp + (size_t)64 * QKC, kd + 8192);
  gload16(vgp, vd);
  gload16(vgp + 64, vd + 8192);
  kgp += (size_t)128 * QKC; vgp += 128;
  asm volatile("s_waitcnt vmcnt(0)" ::: "memory");
  __syncthreads();

  #define CVTSW(SA, q, DST) {                                                       \
    unsigned X0, X1, Y0, Y1;                                                        \
    asm("v_cvt_pk_bf16_f32 %0, %1, %2" : "=v"(X0) : "v"(SA[q*8+0]), "v"(SA[q*8+1]));\
    asm("v_cvt_pk_bf16_f32 %0, %1, %2" : "=v"(X1) : "v"(SA[q*8+2]), "v"(SA[q*8+3]));\
    asm("v_cvt_pk_bf16_f32 %0, %1, %2" : "=v"(Y0) : "v"(SA[q*8+4]), "v"(SA[q*8+5]));\
    asm("v_cvt_pk_bf16_f32 %0, %1, %2" : "=v"(Y1) : "v"(SA[q*8+6]), "v"(SA[q*8+7]));\
    asm("v_permlane32_swap_b32 %0, %1" : "+v"(X0), "+v"(Y0));                       \
    asm("v_permlane32_swap_b32 %0, %1" : "+v"(X1), "+v"(Y1));                       \
    union { unsigned u[4]; bf16x8 v; } pu = {{X0, X1, Y0, Y1}};                     \
    DST = pu.v; }

  // One 64-j subtile: QK into SA (8 MFMA).
  #define SUB_QK(KRBASE, SA0, SA1) {                                               \
    const unsigned short* Kr = (KRBASE);                                           \
    _Pragma("unroll")                                                              \
    for (int kk = 0; kk < 4; kk++) {                                               \
      bf16x8 ak = *(const bf16x8*)&Kr[rbk[kk]];                                    \
      SA0 = __builtin_amdgcn_mfma_f32_32x32x16_bf16(ak, fq[kk], SA0, 0, 0, 0);     \
    }                                                                              \
    _Pragma("unroll")                                                              \
    for (int kk = 0; kk < 4; kk++) {                                               \
      bf16x8 ak = *(const bf16x8*)&Kr[rbk[kk] + 2048];                             \
      SA1 = __builtin_amdgcn_mfma_f32_32x32x16_bf16(ak, fq[kk], SA1, 0, 0, 0);     \
    }}

  // exp2 + cvt + PV (8 MFMA) + lane-local l sum (VALU, hides under PV).
  #define SUB_SMPV(SA0, SA1, VRBASE) {                                             \
    _Pragma("unroll")                                                              \
    for (int r = 0; r < 16; r++) {                                                 \
      SA0[r] = __builtin_amdgcn_exp2f(SA0[r]);                                     \
      SA1[r] = __builtin_amdgcn_exp2f(SA1[r]);                                     \
    }                                                                              \
    bf16x8 p0_, p1_, p2_, p3_;                                                     \
    CVTSW(SA0, 0, p0_);                                                            \
    CVTSW(SA0, 1, p1_);                                                            \
    CVTSW(SA1, 0, p2_);                                                            \
    CVTSW(SA1, 1, p3_);                                                            \
    const unsigned short* Vr = (VRBASE);                                           \
    __builtin_amdgcn_s_setprio(1);                                                 \
    {                                                                              \
      bf16x8 bv0 = *(const bf16x8*)&Vr[rbk[0]];                                    \
      bf16x8 bv1 = *(const bf16x8*)&Vr[rbk[0] + 2048];                             \
      acc_o0 = __builtin_amdgcn_mfma_f32_32x32x16_bf16(p0_, bv0, acc_o0, 0, 0, 0); \
      acc_o1 = __builtin_amdgcn_mfma_f32_32x32x16_bf16(p0_, bv1, acc_o1, 0, 0, 0); \
    }                                                                              \
    {                                                                              \
      bf16x8 bv0 = *(const bf16x8*)&Vr[rbk[1]];                                    \
      bf16x8 bv1 = *(const bf16x8*)&Vr[rbk[1] + 2048];                             \
      acc_o0 = __builtin_amdgcn_mfma_f32_32x32x16_bf16(p1_, bv0, acc_o0, 0, 0, 0); \
      acc_o1 = __builtin_amdgcn_mfma_f32_32x32x16_bf16(p1_, bv1, acc_o1, 0, 0, 0); \
    }                                                                              \
    {                                                                              \
      bf16x8 bv0 = *(const bf16x8*)&Vr[rbk[2]];                                    \
      bf16x8 bv1 = *(const bf16x8*)&Vr[rbk[2] + 2048];                             \
      acc_o0 = __builtin_amdgcn_mfma_f32_32x32x16_bf16(p2_, bv0, acc_o0, 0, 0, 0); \
      acc_o1 = __builtin_amdgcn_mfma_f32_32x32x16_bf16(p2_, bv1, acc_o1, 0, 0, 0); \
    }                                                                              \
    {                                                                              \
      bf16x8 bv0 = *(const bf16x8*)&Vr[rbk[3]];                                    \
      bf16x8 bv1 = *(const bf16x8*)&Vr[rbk[3] + 2048];                             \
      acc_o0 = __builtin_amdgcn_mfma_f32_32x32x16_bf16(p3_, bv0, acc_o0, 0, 0, 0); \
      acc_o1 = __builtin_amdgcn_mfma_f32_32x32x16_bf16(p3_, bv1, acc_o1, 0, 0, 0); \
    }                                                                              \
    __builtin_amdgcn_s_setprio(0);                                                 \
    float ls0 = 0.f, ls1 = 0.f;                                                    \
    _Pragma("unroll")                                                              \
    for (int r = 0; r < 16; r++) { ls0 += SA0[r]; ls1 += SA1[r]; }                 \
    l_run += ls0 + ls1; }

  // ROUND t (128 j): stage(t+1)->other buf; QK(j0); QK(j1); SM+PV(j0); SM+PV(j1);
  // vmcnt drain + barrier.
  #define ROUND(BUF, t) {                                                          \
    if ((t) + 1 < 32) {                                                            \
      unsigned short* kdn = &slds[((BUF) ^ 1) * 16384 + w * 512];                  \
      unsigned short* vdn = kdn + 4096;                                            \
      gload16(kgp, kdn);                                                           \
      gload16(kgp + (size_t)64 * QKC, kdn + 8192);                                 \
      gload16(vgp, vdn);                                                           \
      gload16(vgp + 64, vdn + 8192);                                               \
      kgp += (size_t)128 * QKC; vgp += 128;                                        \
    }                                                                              \
    const unsigned short* base = &slds[(BUF) * 16384];                             \
    f32x16 sa0 = {}, sa1 = {}, sb0 = {}, sb1 = {};                                 \
    __builtin_amdgcn_s_setprio(1);                                                 \
    SUB_QK(base, sa0, sa1)                                                         \
    SUB_QK(base + 8192, sb0, sb1)                                                  \
    __builtin_amdgcn_s_setprio(0);                                                 \
    SUB_SMPV(sa0, sa1, base + 4096)                                                \
    SUB_SMPV(sb0, sb1, base + 12288)                                               \
    asm volatile("s_waitcnt vmcnt(0) lgkmcnt(0)" ::: "memory");                    \
    __builtin_amdgcn_s_barrier(); }

  for (int t = 0; t < 32; t += 2) {
    ROUND(0, t)
    ROUND(1, t + 1)
  }
  #undef ROUND
  #undef SUB_SMPV
  #undef SUB_QK
  #undef CVTSW

  // epilogue: combine cross-hi halves, fetch l per output row via lane shuffle
  float l_tot = l_run + __shfl_xor(l_run, 32);
  #pragma unroll
  for (int r = 0; r < 16; r++) {
    int i = (r & 3) + 8 * (r >> 2) + 4 * hi;
    float inv = __builtin_amdgcn_rcpf(__shfl(l_tot, i));
    size_t rowo = ((size_t)b * NS + (iw + i)) * NC + h * HD;
    ob[rowo + l31]      = f2bf_rn(acc_o0[r] * inv);
    ob[rowo + 32 + l31] = f2bf_rn(acc_o1[r] * inv);
  }
}

// ---------------- K5: proj GEMM + bias + residual (global_load_lds staging, BK=64) ----------------
__global__ __launch_bounds__(256) void proj_gemm_k(const unsigned short* __restrict__ wpb,
                                                   const float* __restrict__ bp,
                                                   const unsigned short* __restrict__ obuf,
                                                   const float* __restrict__ x,
                                                   float* __restrict__ out) {
  int b = blockIdx.z;
  int m0 = blockIdx.x * 128, n0 = blockIdx.y * 128;  // m = o, n = s
  __shared__ unsigned short alds[128 * 64];
  __shared__ unsigned short blds[128 * 64];
  const unsigned short* Bt = obuf + (size_t)b * NS * NC;
  int tid = threadIdx.x;
  int l = tid & 63, w = tid >> 6;
  int wr = w >> 1, wc = w & 1;
  int lm = l & 15, lg = l >> 4;
  int lrow = l >> 3, lcb = l & 7;
  f32x4 acc[4][4];
  #pragma unroll
  for (int mi = 0; mi < 4; mi++)
    #pragma unroll
    for (int ni = 0; ni < 4; ni++) acc[mi][ni] = (f32x4){0.f, 0.f, 0.f, 0.f};

  for (int k0 = 0; k0 < NC; k0 += 64) {
    #pragma unroll
    for (int j = 0; j < 4; j++) {
      int row = w * 32 + j * 8 + lrow;
      int scb = lcb ^ (row & 7);
      gload16(wpb + (size_t)(m0 + row) * NC + k0 + scb * 8, &alds[(w * 4 + j) * 512]);
      gload16(Bt  + (size_t)(n0 + row) * NC + k0 + scb * 8, &blds[(w * 4 + j) * 512]);
    }
    __syncthreads();
    #pragma unroll
    for (int ks = 0; ks < 2; ks++) {
      bf16x8 af[4], bfr[4];
      #pragma unroll
      for (int mi = 0; mi < 4; mi++) {
        int row = wr * 64 + mi * 16 + lm;
        af[mi] = *(const bf16x8*)&alds[((row << 6) + (ks << 5) + (lg << 3)) ^ ((row & 7) << 3)];
      }
      #pragma unroll
      for (int ni = 0; ni < 4; ni++) {
        int row = wc * 64 + ni * 16 + lm;
        bfr[ni] = *(const bf16x8*)&blds[((row << 6) + (ks << 5) + (lg << 3)) ^ ((row & 7) << 3)];
      }
      #pragma unroll
      for (int mi = 0; mi < 4; mi++)
        #pragma unroll
        for (int ni = 0; ni < 4; ni++)
          acc[mi][ni] = __builtin_amdgcn_mfma_f32_16x16x32_bf16(af[mi], bfr[ni], acc[mi][ni], 0, 0, 0);
    }
    __syncthreads();
  }
  #pragma unroll
  for (int mi = 0; mi < 4; mi++) {
    #pragma unroll
    for (int q = 0; q < 4; q++) {
      int o = m0 + wr * 64 + mi * 16 + lg * 4 + q;
      float bias = bp[o];
      #pragma unroll
      for (int ni = 0; ni < 4; ni++) {
        int s = n0 + wc * 64 + ni * 16 + lm;
        size_t idx = ((size_t)b * NC + o) * NS + s;
        out[idx] = acc[mi][ni][q] + bias + x[idx];
      }
    }
  }
}

extern "C" void kernel_launch(void* const* d_in, const int* in_sizes, int n_in,
                              void* d_out, int out_size, void* d_ws, size_t ws_size,
                              hipStream_t stream) {
  const float* x  = (const float*)d_in[0];
  const float* nw = (const float*)d_in[1];
  const float* nb = (const float*)d_in[2];
  const float* wq = (const float*)d_in[3];
  const float* bq = (const float*)d_in[4];
  const float* wp = (const float*)d_in[5];
  const float* bp = (const float*)d_in[6];
  float* out = (float*)d_out;

  char* ws = (char*)d_ws;
  size_t off = 0;
  off += 1024;  // (legacy stats slot, unused)
  unsigned short* ht  = (unsigned short*)(ws + off); off += (size_t)NB * NS * NC * 2;   // 16.78 MB
  unsigned short* qk  = (unsigned short*)(ws + off); off += (size_t)NB * NS * QKC * 2;  // 33.55 MB
  unsigned short* vt  = (unsigned short*)(ws + off); off += (size_t)NB * NS * NC * 2;   // 16.78 MB
  unsigned short* wqb = (unsigned short*)(ws + off); off += (size_t)3 * NC * NC * 2;    // 1.57 MB
  unsigned short* wpb = (unsigned short*)(ws + off); off += (size_t)NC * NC * 2;        // 0.52 MB
  unsigned short* ob  = ht;          // lifetime-disjoint alias
  float* pstats = (float*)qk;        // lifetime-disjoint: used before qkv_gemm writes qk

  prep_k<<<dim3(1024), 256, 0, stream>>>(x, pstats, wq, wp, wqb, wpb);
  gn_apply_k<<<dim3(NS / 64, NC / 64, NB), 256, 0, stream>>>(x, pstats, nw, nb, ht);
  qkv_gemm_k<<<dim3(NS / 128, 1536 / 128, NB), 256, 0, stream>>>(ht, wqb, bq, qk, vt);
  attn_k<<<dim3(512), 512, 0, stream>>>(qk, vt, ob);
  proj_gemm_k<<<dim3(NC / 128, NS / 128, NB), 256, 0, stream>>>(wpb, bp, ob, x, out);
}

// Round 19
// 216.798 us; speedup vs baseline: 1.0115x; 1.0115x over previous
//
#include <hip/hip_runtime.h>
#include <hip/hip_bf16.h>

#define NB 4
#define NC 512
#define NS 4096
#define NH 8
#define HD 64
#define NG 32
#define CPG 16
#define QKC 1024   // Q+K channels in qk buffer
#define CQF 0.18033688f  // 0.125 * log2(e), folded into Q weights

typedef __attribute__((ext_vector_type(8))) short bf16x8;
typedef __attribute__((ext_vector_type(4))) float f32x4;
typedef __attribute__((ext_vector_type(16))) float f32x16;

__device__ __forceinline__ unsigned short f2bf(float f) {
  union { float f; unsigned int u; } v; v.f = f;
  unsigned int r = v.u + 0x7FFFu + ((v.u >> 16) & 1u);
  return (unsigned short)(r >> 16);
}

__device__ __forceinline__ unsigned short f2bf_rn(float f) {
  union { __hip_bfloat16 h; unsigned short u; } cv;
  cv.h = __float2bfloat16(f);
  return cv.u;
}

// async global->LDS, 16B per lane. LDS base must be wave-uniform; source is per-lane.
__device__ __forceinline__ void gload16(const unsigned short* g, unsigned short* s) {
  __builtin_amdgcn_global_load_lds(
      (const __attribute__((address_space(1))) unsigned int*)g,
      (__attribute__((address_space(3))) unsigned int*)s, 16, 0, 0);
}

// ---------------- K1: fused prep: gn partial stats (blocks 0..511) + weight cvt (blocks 512..1023) ----------------
__global__ __launch_bounds__(256) void prep_k(const float* __restrict__ x,
                                              float* __restrict__ pstats,
                                              const float* __restrict__ wq,
                                              const float* __restrict__ wp,
                                              unsigned short* __restrict__ wqb,
                                              unsigned short* __restrict__ wpb) {
  int bid = blockIdx.x;
  if (bid < NB * NG * 4) {
    int bgq = bid;
    const float4* xp = (const float4*)(x + (size_t)bgq * (CPG * NS / 4));
    float s = 0.f, s2 = 0.f;
    #pragma unroll 4
    for (int i = threadIdx.x; i < CPG * NS / 16; i += 256) {
      float4 v = xp[i];
      s  += v.x + v.y + v.z + v.w;
      s2 += v.x * v.x + v.y * v.y + v.z * v.z + v.w * v.w;
    }
    #pragma unroll
    for (int off = 32; off > 0; off >>= 1) {
      s  += __shfl_down(s, off);
      s2 += __shfl_down(s2, off);
    }
    __shared__ float rs[4], rs2[4];
    int wid = threadIdx.x >> 6;
    if ((threadIdx.x & 63) == 0) { rs[wid] = s; rs2[wid] = s2; }
    __syncthreads();
    if (threadIdx.x == 0) {
      pstats[bgq * 2]     = rs[0] + rs[1] + rs[2] + rs[3];
      pstats[bgq * 2 + 1] = rs2[0] + rs2[1] + rs2[2] + rs2[3];
    }
  } else {
    const int nq8 = 3 * NC * NC / 8, np8 = NC * NC / 8, se8 = NC * NC / 8;
    int i = (bid - NB * NG * 4) * 256 + threadIdx.x;
    if (i >= nq8 + np8) return;
    const float* src;
    unsigned short* dst;
    float sc;
    int j;
    if (i < nq8) { src = wq; dst = wqb; j = i; sc = (i < se8) ? CQF : 1.0f; }
    else         { src = wp; dst = wpb; j = i - nq8; sc = 1.0f; }
    const float4* s = (const float4*)src + (size_t)j * 2;
    float4 a = s[0], b = s[1];
    ushort4 u0 = make_ushort4(f2bf_rn(a.x * sc), f2bf_rn(a.y * sc),
                              f2bf_rn(a.z * sc), f2bf_rn(a.w * sc));
    ushort4 u1 = make_ushort4(f2bf_rn(b.x * sc), f2bf_rn(b.y * sc),
                              f2bf_rn(b.z * sc), f2bf_rn(b.w * sc));
    uint4 o;
    o.x = (unsigned)u0.x | ((unsigned)u0.y << 16);
    o.y = (unsigned)u0.z | ((unsigned)u0.w << 16);
    o.z = (unsigned)u1.x | ((unsigned)u1.y << 16);
    o.w = (unsigned)u1.z | ((unsigned)u1.w << 16);
    *((uint4*)dst + j) = o;
  }
}

// ---------------- K2: normalize + transpose -> ht[b][s][c] (bf16); combines partial stats ----------------
__global__ __launch_bounds__(256) void gn_apply_k(const float* __restrict__ x,
                                                  const float* __restrict__ pstats,
                                                  const float* __restrict__ nw,
                                                  const float* __restrict__ nb,
                                                  unsigned short* __restrict__ ht) {
  int st = blockIdx.x, ct = blockIdx.y, b = blockIdx.z;
  int c0 = ct * 64, s0 = st * 64;
  __shared__ unsigned short lds[64][72];
  for (int idx = threadIdx.x; idx < 1024; idx += 256) {
    int row = idx >> 4, c4 = idx & 15;
    int c = c0 + row;
    int gi = (b * NG + (c >> 4)) * 4;
    const float4* pq = (const float4*)(pstats + gi * 2);
    float4 p01 = pq[0], p23 = pq[1];
    float sum = p01.x + p01.z + p23.x + p23.z;
    float ssq = p01.y + p01.w + p23.y + p23.w;
    float inv_n = 1.0f / (CPG * NS);
    float mu = sum * inv_n;
    float var = ssq * inv_n - mu * mu;
    float rstd = rsqrtf(var + 1e-5f);
    float sw = nw[c] * rstd;
    float sb = nb[c] - mu * sw;
    float4 v = *(const float4*)(x + ((size_t)b * NC + c) * NS + s0 + c4 * 4);
    ushort4 u = make_ushort4(f2bf(v.x * sw + sb), f2bf(v.y * sw + sb),
                             f2bf(v.z * sw + sb), f2bf(v.w * sw + sb));
    *(ushort4*)&lds[row][c4 * 4] = u;
  }
  __syncthreads();
  for (int idx = threadIdx.x; idx < 1024; idx += 256) {
    int i = idx >> 4, ch = idx & 15;
    ushort4 u = make_ushort4(lds[ch * 4 + 0][i], lds[ch * 4 + 1][i],
                             lds[ch * 4 + 2][i], lds[ch * 4 + 3][i]);
    *(ushort4*)(ht + ((size_t)b * NS + s0 + i) * NC + c0 + ch * 4) = u;
  }
}

// ---------------- K3: QKV GEMM, global_load_lds staging (BK=64, XOR-swizzled LDS) ----------------
__global__ __launch_bounds__(256) void qkv_gemm_k(const unsigned short* __restrict__ ht,
                                                  const unsigned short* __restrict__ wqb,
                                                  const float* __restrict__ bq,
                                                  unsigned short* __restrict__ qk,
                                                  unsigned short* __restrict__ vt) {
  int b = blockIdx.z;
  int m0 = blockIdx.x * 128, n0 = blockIdx.y * 128;  // m = s, n = o
  __shared__ unsigned short alds[128 * 64];
  __shared__ unsigned short blds[128 * 64];
  const unsigned short* A = ht + (size_t)b * NS * NC;
  int tid = threadIdx.x;
  int l = tid & 63, w = tid >> 6;
  int wr = w >> 1, wc = w & 1;
  int lm = l & 15, lg = l >> 4;
  int lrow = l >> 3, lcb = l & 7;
  f32x4 acc[4][4];
  #pragma unroll
  for (int mi = 0; mi < 4; mi++)
    #pragma unroll
    for (int ni = 0; ni < 4; ni++) acc[mi][ni] = (f32x4){0.f, 0.f, 0.f, 0.f};

  for (int k0 = 0; k0 < NC; k0 += 64) {
    #pragma unroll
    for (int j = 0; j < 4; j++) {
      int row = w * 32 + j * 8 + lrow;
      int scb = lcb ^ (row & 7);
      gload16(A   + (size_t)(m0 + row) * NC + k0 + scb * 8, &alds[(w * 4 + j) * 512]);
      gload16(wqb + (size_t)(n0 + row) * NC + k0 + scb * 8, &blds[(w * 4 + j) * 512]);
    }
    __syncthreads();
    #pragma unroll
    for (int ks = 0; ks < 2; ks++) {
      bf16x8 af[4], bfr[4];
      #pragma unroll
      for (int mi = 0; mi < 4; mi++) {
        int row = wr * 64 + mi * 16 + lm;
        af[mi] = *(const bf16x8*)&alds[((row << 6) + (ks << 5) + (lg << 3)) ^ ((row & 7) << 3)];
      }
      #pragma unroll
      for (int ni = 0; ni < 4; ni++) {
        int row = wc * 64 + ni * 16 + lm;
        bfr[ni] = *(const bf16x8*)&blds[((row << 6) + (ks << 5) + (lg << 3)) ^ ((row & 7) << 3)];
      }
      #pragma unroll
      for (int mi = 0; mi < 4; mi++)
        #pragma unroll
        for (int ni = 0; ni < 4; ni++)
          acc[mi][ni] = __builtin_amdgcn_mfma_f32_16x16x32_bf16(af[mi], bfr[ni], acc[mi][ni], 0, 0, 0);
    }
    __syncthreads();
  }
  if (n0 < QKC) {
    #pragma unroll
    for (int mi = 0; mi < 4; mi++) {
      #pragma unroll
      for (int ni = 0; ni < 4; ni++) {
        int o = n0 + wc * 64 + ni * 16 + lm;
        float bias = bq[o];
        if (o < NC) bias *= CQF;  // Q rows: weight pre-scaled, bias scaled to match
        #pragma unroll
        for (int q = 0; q < 4; q++) {
          int s = m0 + wr * 64 + mi * 16 + lg * 4 + q;
          qk[((size_t)b * NS + s) * QKC + o] = f2bf(acc[mi][ni][q] + bias);
        }
      }
    }
  } else {
    #pragma unroll
    for (int mi = 0; mi < 4; mi++) {
      int s0 = m0 + wr * 64 + mi * 16 + lg * 4;
      #pragma unroll
      for (int ni = 0; ni < 4; ni++) {
        int o = n0 + wc * 64 + ni * 16 + lm;
        float bias = bq[o];
        int dg = o - QKC;  // 0..511 == h*64+d
        ushort4 u = make_ushort4(f2bf(acc[mi][ni][0] + bias), f2bf(acc[mi][ni][1] + bias),
                                 f2bf(acc[mi][ni][2] + bias), f2bf(acc[mi][ni][3] + bias));
        *(ushort4*)(vt + ((size_t)b * NC + dg) * NS + s0) = u;
      }
    }
  }
}

// ---------------- K4: flash attention ----------------
// 8 waves / 256 Q-rows; gload_lds staging; XCD-pinned; KVBLK=128 per round (2 subtiles):
// QK(j1) covers QK(j0)'s drain, exp2(j0) covers QK(j1)'s drain, exp2(j1) overlaps PV(j0).
// PV in-round -> V read straight from current LDS buffer (no V reg ping-pong).
__global__ __launch_bounds__(512) void attn_k(const unsigned short* __restrict__ qk,
                                              const unsigned short* __restrict__ vt,
                                              unsigned short* __restrict__ ob) {
  int bid = blockIdx.x;
  int xcd = bid & 7, g = bid >> 3;
  int pair = xcd * 4 + (g >> 4);   // bijective: 32 (b,h) pairs, 4 per XCD
  int qt = g & 15;
  int h = pair & 7, b = pair >> 3;
  int tid = threadIdx.x;
  int l = tid & 63, w = tid >> 6;  // w in 0..7
  int l31 = l & 31, hi = l >> 5;
  // [buf:2][K0:4096|V0:4096|K1:4096|V1:4096] shorts = 64 KB
  __shared__ unsigned short slds[32768];
  const unsigned short* qkb = qk + (size_t)b * NS * QKC;
  const unsigned short* vtb = vt + ((size_t)b * NC + h * HD) * NS;
  int iw = qt * 256 + w * 32;

  bf16x8 fq[4];
  #pragma unroll
  for (int kk = 0; kk < 4; kk++)
    fq[kk] = *(const bf16x8*)(qkb + (size_t)(iw + l31) * QKC + h * HD + kk * 16 + hi * 8);

  bf16x8 ones;
  #pragma unroll
  for (int e = 0; e < 8; e++) ones[e] = (short)0x3F80;

  int rb = (((l31 << 6) + (hi << 3)) ^ ((l31 & 7) << 3));
  int rbk[4] = { rb, rb ^ 16, rb ^ 32, rb ^ 48 };

  // gload staging: wave w covers rows w*8..w*8+8 of each 64-row subtile
  int kr = w * 8 + (l >> 3);
  int scb = (l & 7) ^ (l >> 3);    // (l&7) ^ (kr&7); +64-row offsets preserve kr&7
  const unsigned short* kgp = qkb + NC + h * HD + (size_t)kr * QKC + scb * 8;
  const unsigned short* vgp = vtb + (size_t)kr * NS + scb * 8;
  unsigned short* kd = &slds[w * 512];          // K0 dest (buf0); +8192 for K1; +16384 for buf1
  unsigned short* vd = &slds[4096 + w * 512];   // V0 dest

  f32x16 acc_o0 = {}, acc_o1 = {}, acc_l = {};

  // prologue: round-0 tile (128 j) -> buf0
  gload16(kgp, kd);
  gload16(kgp + (size_t)64 * QKC, kd + 8192);
  gload16(vgp, vd);
  gload16(vgp + 64, vd + 8192);
  kgp += (size_t)128 * QKC; vgp += 128;
  asm volatile("s_waitcnt vmcnt(0)" ::: "memory");
  __syncthreads();

  #define CVTSW(SA, q, DST) {                                                       \
    unsigned X0, X1, Y0, Y1;                                                        \
    asm("v_cvt_pk_bf16_f32 %0, %1, %2" : "=v"(X0) : "v"(SA[q*8+0]), "v"(SA[q*8+1]));\
    asm("v_cvt_pk_bf16_f32 %0, %1, %2" : "=v"(X1) : "v"(SA[q*8+2]), "v"(SA[q*8+3]));\
    asm("v_cvt_pk_bf16_f32 %0, %1, %2" : "=v"(Y0) : "v"(SA[q*8+4]), "v"(SA[q*8+5]));\
    asm("v_cvt_pk_bf16_f32 %0, %1, %2" : "=v"(Y1) : "v"(SA[q*8+6]), "v"(SA[q*8+7]));\
    asm("v_permlane32_swap_b32 %0, %1" : "+v"(X0), "+v"(Y0));                       \
    asm("v_permlane32_swap_b32 %0, %1" : "+v"(X1), "+v"(Y1));                       \
    union { unsigned u[4]; bf16x8 v; } pu = {{X0, X1, Y0, Y1}};                     \
    DST = pu.v; }

  // One 64-j subtile: QK into SA (8 MFMA). SUB_QK only; softmax+PV split out so
  // independent work can interleave.
  #define SUB_QK(KRBASE, SA0, SA1) {                                               \
    const unsigned short* Kr = (KRBASE);                                           \
    _Pragma("unroll")                                                              \
    for (int kk = 0; kk < 4; kk++) {                                               \
      bf16x8 ak = *(const bf16x8*)&Kr[rbk[kk]];                                    \
      SA0 = __builtin_amdgcn_mfma_f32_32x32x16_bf16(ak, fq[kk], SA0, 0, 0, 0);     \
    }                                                                              \
    _Pragma("unroll")                                                              \
    for (int kk = 0; kk < 4; kk++) {                                               \
      bf16x8 ak = *(const bf16x8*)&Kr[rbk[kk] + 2048];                             \
      SA1 = __builtin_amdgcn_mfma_f32_32x32x16_bf16(ak, fq[kk], SA1, 0, 0, 0);     \
    }}

  #define SUB_SMPV(SA0, SA1, VRBASE) {                                             \
    _Pragma("unroll")                                                              \
    for (int r = 0; r < 16; r++) {                                                 \
      SA0[r] = __builtin_amdgcn_exp2f(SA0[r]);                                     \
      SA1[r] = __builtin_amdgcn_exp2f(SA1[r]);                                     \
    }                                                                              \
    bf16x8 p0_, p1_, p2_, p3_;                                                     \
    CVTSW(SA0, 0, p0_);                                                            \
    CVTSW(SA0, 1, p1_);                                                            \
    CVTSW(SA1, 0, p2_);                                                            \
    CVTSW(SA1, 1, p3_);                                                            \
    const unsigned short* Vr = (VRBASE);                                           \
    __builtin_amdgcn_s_setprio(1);                                                 \
    {                                                                              \
      bf16x8 bv0 = *(const bf16x8*)&Vr[rbk[0]];                                    \
      bf16x8 bv1 = *(const bf16x8*)&Vr[rbk[0] + 2048];                             \
      acc_l  = __builtin_amdgcn_mfma_f32_32x32x16_bf16(p0_, ones, acc_l, 0, 0, 0); \
      acc_o0 = __builtin_amdgcn_mfma_f32_32x32x16_bf16(p0_, bv0, acc_o0, 0, 0, 0); \
      acc_o1 = __builtin_amdgcn_mfma_f32_32x32x16_bf16(p0_, bv1, acc_o1, 0, 0, 0); \
    }                                                                              \
    {                                                                              \
      bf16x8 bv0 = *(const bf16x8*)&Vr[rbk[1]];                                    \
      bf16x8 bv1 = *(const bf16x8*)&Vr[rbk[1] + 2048];                             \
      acc_l  = __builtin_amdgcn_mfma_f32_32x32x16_bf16(p1_, ones, acc_l, 0, 0, 0); \
      acc_o0 = __builtin_amdgcn_mfma_f32_32x32x16_bf16(p1_, bv0, acc_o0, 0, 0, 0); \
      acc_o1 = __builtin_amdgcn_mfma_f32_32x32x16_bf16(p1_, bv1, acc_o1, 0, 0, 0); \
    }                                                                              \
    {                                                                              \
      bf16x8 bv0 = *(const bf16x8*)&Vr[rbk[2]];                                    \
      bf16x8 bv1 = *(const bf16x8*)&Vr[rbk[2] + 2048];                             \
      acc_l  = __builtin_amdgcn_mfma_f32_32x32x16_bf16(p2_, ones, acc_l, 0, 0, 0); \
      acc_o0 = __builtin_amdgcn_mfma_f32_32x32x16_bf16(p2_, bv0, acc_o0, 0, 0, 0); \
      acc_o1 = __builtin_amdgcn_mfma_f32_32x32x16_bf16(p2_, bv1, acc_o1, 0, 0, 0); \
    }                                                                              \
    {                                                                              \
      bf16x8 bv0 = *(const bf16x8*)&Vr[rbk[3]];                                    \
      bf16x8 bv1 = *(const bf16x8*)&Vr[rbk[3] + 2048];                             \
      acc_l  = __builtin_amdgcn_mfma_f32_32x32x16_bf16(p3_, ones, acc_l, 0, 0, 0); \
      acc_o0 = __builtin_amdgcn_mfma_f32_32x32x16_bf16(p3_, bv0, acc_o0, 0, 0, 0); \
      acc_o1 = __builtin_amdgcn_mfma_f32_32x32x16_bf16(p3_, bv1, acc_o1, 0, 0, 0); \
    }                                                                              \
    __builtin_amdgcn_s_setprio(0); }

  // ROUND t (128 j): stage(t+1)->other buf; QK(j0); QK(j1); SM+PV(j0); SM+PV(j1);
  // vmcnt drain + barrier.
  #define ROUND(BUF, t) {                                                          \
    if ((t) + 1 < 32) {                                                            \
      unsigned short* kdn = &slds[((BUF) ^ 1) * 16384 + w * 512];                  \
      unsigned short* vdn = kdn + 4096;                                            \
      gload16(kgp, kdn);                                                           \
      gload16(kgp + (size_t)64 * QKC, kdn + 8192);                                 \
      gload16(vgp, vdn);                                                           \
      gload16(vgp + 64, vdn + 8192);                                               \
      kgp += (size_t)128 * QKC; vgp += 128;                                        \
    }                                                                              \
    const unsigned short* base = &slds[(BUF) * 16384];                             \
    f32x16 sa0 = {}, sa1 = {}, sb0 = {}, sb1 = {};                                 \
    __builtin_amdgcn_s_setprio(1);                                                 \
    SUB_QK(base, sa0, sa1)                                                         \
    SUB_QK(base + 8192, sb0, sb1)                                                  \
    __builtin_amdgcn_s_setprio(0);                                                 \
    SUB_SMPV(sa0, sa1, base + 4096)                                                \
    SUB_SMPV(sb0, sb1, base + 12288)                                               \
    asm volatile("s_waitcnt vmcnt(0) lgkmcnt(0)" ::: "memory");                    \
    __builtin_amdgcn_s_barrier(); }

  for (int t = 0; t < 32; t += 2) {
    ROUND(0, t)
    ROUND(1, t + 1)
  }
  #undef ROUND
  #undef SUB_SMPV
  #undef SUB_QK
  #undef CVTSW

  #pragma unroll
  for (int r = 0; r < 16; r++) {
    float inv = __builtin_amdgcn_rcpf(acc_l[r]);
    int i = (r & 3) + 8 * (r >> 2) + 4 * hi;
    size_t rowo = ((size_t)b * NS + (iw + i)) * NC + h * HD;
    ob[rowo + l31]      = f2bf_rn(acc_o0[r] * inv);
    ob[rowo + 32 + l31] = f2bf_rn(acc_o1[r] * inv);
  }
}

// ---------------- K5: proj GEMM + bias + residual (global_load_lds staging, BK=64) ----------------
__global__ __launch_bounds__(256) void proj_gemm_k(const unsigned short* __restrict__ wpb,
                                                   const float* __restrict__ bp,
                                                   const unsigned short* __restrict__ obuf,
                                                   const float* __restrict__ x,
                                                   float* __restrict__ out) {
  int b = blockIdx.z;
  int m0 = blockIdx.x * 128, n0 = blockIdx.y * 128;  // m = o, n = s
  __shared__ unsigned short alds[128 * 64];
  __shared__ unsigned short blds[128 * 64];
  const unsigned short* Bt = obuf + (size_t)b * NS * NC;
  int tid = threadIdx.x;
  int l = tid & 63, w = tid >> 6;
  int wr = w >> 1, wc = w & 1;
  int lm = l & 15, lg = l >> 4;
  int lrow = l >> 3, lcb = l & 7;
  f32x4 acc[4][4];
  #pragma unroll
  for (int mi = 0; mi < 4; mi++)
    #pragma unroll
    for (int ni = 0; ni < 4; ni++) acc[mi][ni] = (f32x4){0.f, 0.f, 0.f, 0.f};

  for (int k0 = 0; k0 < NC; k0 += 64) {
    #pragma unroll
    for (int j = 0; j < 4; j++) {
      int row = w * 32 + j * 8 + lrow;
      int scb = lcb ^ (row & 7);
      gload16(wpb + (size_t)(m0 + row) * NC + k0 + scb * 8, &alds[(w * 4 + j) * 512]);
      gload16(Bt  + (size_t)(n0 + row) * NC + k0 + scb * 8, &blds[(w * 4 + j) * 512]);
    }
    __syncthreads();
    #pragma unroll
    for (int ks = 0; ks < 2; ks++) {
      bf16x8 af[4], bfr[4];
      #pragma unroll
      for (int mi = 0; mi < 4; mi++) {
        int row = wr * 64 + mi * 16 + lm;
        af[mi] = *(const bf16x8*)&alds[((row << 6) + (ks << 5) + (lg << 3)) ^ ((row & 7) << 3)];
      }
      #pragma unroll
      for (int ni = 0; ni < 4; ni++) {
        int row = wc * 64 + ni * 16 + lm;
        bfr[ni] = *(const bf16x8*)&blds[((row << 6) + (ks << 5) + (lg << 3)) ^ ((row & 7) << 3)];
      }
      #pragma unroll
      for (int mi = 0; mi < 4; mi++)
        #pragma unroll
        for (int ni = 0; ni < 4; ni++)
          acc[mi][ni] = __builtin_amdgcn_mfma_f32_16x16x32_bf16(af[mi], bfr[ni], acc[mi][ni], 0, 0, 0);
    }
    __syncthreads();
  }
  #pragma unroll
  for (int mi = 0; mi < 4; mi++) {
    #pragma unroll
    for (int q = 0; q < 4; q++) {
      int o = m0 + wr * 64 + mi * 16 + lg * 4 + q;
      float bias = bp[o];
      #pragma unroll
      for (int ni = 0; ni < 4; ni++) {
        int s = n0 + wc * 64 + ni * 16 + lm;
        size_t idx = ((size_t)b * NC + o) * NS + s;
        out[idx] = acc[mi][ni][q] + bias + x[idx];
      }
    }
  }
}

extern "C" void kernel_launch(void* const* d_in, const int* in_sizes, int n_in,
                              void* d_out, int out_size, void* d_ws, size_t ws_size,
                              hipStream_t stream) {
  const float* x  = (const float*)d_in[0];
  const float* nw = (const float*)d_in[1];
  const float* nb = (const float*)d_in[2];
  const float* wq = (const float*)d_in[3];
  const float* bq = (const float*)d_in[4];
  const float* wp = (const float*)d_in[5];
  const float* bp = (const float*)d_in[6];
  float* out = (float*)d_out;

  char* ws = (char*)d_ws;
  size_t off = 0;
  off += 1024;  // (legacy stats slot, unused)
  unsigned short* ht  = (unsigned short*)(ws + off); off += (size_t)NB * NS * NC * 2;   // 16.78 MB
  unsigned short* qk  = (unsigned short*)(ws + off); off += (size_t)NB * NS * QKC * 2;  // 33.55 MB
  unsigned short* vt  = (unsigned short*)(ws + off); off += (size_t)NB * NS * NC * 2;   // 16.78 MB
  unsigned short* wqb = (unsigned short*)(ws + off); off += (size_t)3 * NC * NC * 2;    // 1.57 MB
  unsigned short* wpb = (unsigned short*)(ws + off); off += (size_t)NC * NC * 2;        // 0.52 MB
  unsigned short* ob  = ht;          // lifetime-disjoint alias
  float* pstats = (float*)qk;        // lifetime-disjoint: used before qkv_gemm writes qk

  prep_k<<<dim3(1024), 256, 0, stream>>>(x, pstats, wq, wp, wqb, wpb);
  gn_apply_k<<<dim3(NS / 64, NC / 64, NB), 256, 0, stream>>>(x, pstats, nw, nb, ht);
  qkv_gemm_k<<<dim3(NS / 128, 1536 / 128, NB), 256, 0, stream>>>(ht, wqb, bq, qk, vt);
  attn_k<<<dim3(512), 512, 0, stream>>>(qk, vt, ob);
  proj_gemm_k<<<dim3(NC / 128, NS / 128, NB), 256, 0, stream>>>(wpb, bp, ob, x, out);
}